// Round 7
// baseline (112.684 us; speedup 1.0000x reference)
//
#include <hip/hip_runtime.h>
#include <math.h>

// Problem constants
#define HW 64
#define NB 2
#define NCIN 128
#define NCH 32

typedef float f32x4 __attribute__((ext_vector_type(4)));

typedef __attribute__((address_space(3))) void lds_void;
typedef const __attribute__((address_space(1))) void g_void;
__device__ __forceinline__ void load_lds16(const float* g, float* l) {
    __builtin_amdgcn_global_load_lds((g_void*)g, (lds_void*)l, 16, 0, 0);
}

// ws layout:
//   fm   : float[2*64*64]            @ 0        (32768 B)
//   offs : int4 [8192]               @ 32768    (131072 B)
//   wts  : float4[8192]              @ 163840   (131072 B)

// ---------------- kernel 1: fm = mean over 128 channels ----------------
__global__ __launch_bounds__(256) void k_mean(const float* __restrict__ feat,
                                              float* __restrict__ fm) {
    int bh = blockIdx.x;            // b*64 + h
    int w  = threadIdx.x & 63;
    int cg = threadIdx.x >> 6;      // 0..3, each sums 32 channels
    int b = bh >> 6, h = bh & 63;
    const float* base = feat + ((size_t)(b * NCIN) * 64 + h) * 64 + w;
    float s = 0.f;
    #pragma unroll
    for (int c = 0; c < 32; ++c)
        s += base[(size_t)(cg * 32 + c) * 4096];
    __shared__ float red[4][64];
    red[cg][w] = s;
    __syncthreads();
    if (cg == 0) {
        float tot = red[0][w] + red[1][w] + red[2][w] + red[3][w];
        fm[bh * 64 + w] = tot * (1.f / 128.f);
    }
}

// ------------- kernel 2: per-position offsets/weights/gain -------------
__global__ __launch_bounds__(256) void k_params(
    const float* __restrict__ fm,
    const float* __restrict__ W_in, const float* __restrict__ b_in,
    const float* __restrict__ W_dw, const float* __restrict__ b_dw,
    const float* __restrict__ W_ofs, const float* __restrict__ W_a,
    const float* __restrict__ b_a, const float* __restrict__ lam,
    int4* __restrict__ offs, float4* __restrict__ wts)
{
    __shared__ float WD[NCH * 25];
    __shared__ float Wi[NCH], Bi[NCH], Bd[NCH], Wo0[NCH], Wo1[NCH], Wa_s[NCH];
    int t = threadIdx.x;
    for (int k = t; k < NCH * 25; k += 256) WD[k] = W_dw[k];
    if (t < NCH) {
        Wi[t]  = W_in[t];  Bi[t]  = b_in[t]; Bd[t] = b_dw[t];
        Wo0[t] = W_ofs[t]; Wo1[t] = W_ofs[NCH + t];
        Wa_s[t] = W_a[t];
    }
    __syncthreads();

    int p = blockIdx.x * 256 + t;   // 0..8191
    int b = p >> 12;
    int i = (p >> 6) & 63;
    int j = p & 63;

    // 5x5 replicate-padded patch of fm
    float patch[25];
    #pragma unroll
    for (int dy = 0; dy < 5; ++dy) {
        int ry = i + dy - 2; ry = ry < 0 ? 0 : (ry > 63 ? 63 : ry);
        #pragma unroll
        for (int dx = 0; dx < 5; ++dx) {
            int rx = j + dx - 2; rx = rx < 0 ? 0 : (rx > 63 ? 63 : rx);
            patch[dy * 5 + dx] = fm[(b * 64 + ry) * 64 + rx];
        }
    }
    float fmc = patch[12];

    float a0 = 0.f, a1 = 0.f, kA = 0.f, kB = 0.f;
    for (int c = 0; c < NCH; ++c) {
        float s = 0.f, sw = 0.f;
        #pragma unroll
        for (int q = 0; q < 25; ++q) {
            float wv = WD[c * 25 + q];
            s  += patch[q] * wv;
            sw += wv;
        }
        float pre = Wi[c] * s + Bi[c] * sw + Bd[c];
        float zc = pre > 0.f ? pre : 0.f;
        a0 += zc * Wo0[c];
        a1 += zc * Wo1[c];
        kA += Wi[c] * Wa_s[c];
        kB += Bi[c] * Wa_s[c];
    }
    float ga = 1.f + lam[0] * (fmc * kA + kB + b_a[0]);

    float yy = (i + 0.5f) * (1.f / 32.f) - 1.f;
    float xx = (j + 0.5f) * (1.f / 32.f) - 1.f;
    float pos0 = fminf(fmaxf((100.f / 64.f) * tanhf(a0) + yy, -1.f), 1.f); // y
    float pos1 = fminf(fmaxf((100.f / 64.f) * tanhf(a1) + xx, -1.f), 1.f); // x
    float y = (pos0 + 1.f) * 0.5f * 63.f;
    float x = (pos1 + 1.f) * 0.5f * 63.f;
    float y0 = floorf(y), x0 = floorf(x);
    float wy1 = y - y0, wx1 = x - x0;
    float wy0 = 1.f - wy1, wx0 = 1.f - wx1;
    int y0i = (int)y0; y0i = y0i < 0 ? 0 : (y0i > 63 ? 63 : y0i);
    int x0i = (int)x0; x0i = x0i < 0 ? 0 : (x0i > 63 ? 63 : x0i);
    int y1i = y0i + 1 > 63 ? 63 : y0i + 1;
    int x1i = x0i + 1 > 63 ? 63 : x0i + 1;

    int basep = b * 16777216;
    offs[p] = make_int4(basep + (y0i * 64 + x0i) * 4096,
                        basep + (y0i * 64 + x1i) * 4096,
                        basep + (y1i * 64 + x0i) * 4096,
                        basep + (y1i * 64 + x1i) * 4096);
    wts[p] = make_float4(wy0 * wx0 * ga, wy0 * wx1 * ga,
                         wy1 * wx0 * ga, wy1 * wx1 * ga);
}

// ------------- kernel 3: async-staged gather-sample -------------
// block = (bi, ct of 64 channels, jh of 32 j's); 256 threads; LDS 32 KB raw.
// phase1: per wave, 8x async global_load_lds (1 KB each = 4 corners x 256 B
//         of one j). LDS dest wave-uniform+lane*16 (HW rule); bank swizzle
//         via pre-swizzled GLOBAL source: word m holds ch-quad m^(j2&15).
// phase2: combine 4 corners w/ weights in regs; j-contiguous NT stores.
__global__ __launch_bounds__(256) void k_sample(
    const float* __restrict__ gauss,
    const int4* __restrict__ offs, const float4* __restrict__ wts,
    float* __restrict__ out)
{
    __shared__ float ldsbuf[32 * 256];   // 32 KB: j2 slice = 1 KB = 4 x 256 B
    int bid = blockIdx.x;
    // bijective XCD swizzle: 16384 % 8 == 0
    int swz = (bid & 7) * 2048 + (bid >> 3);
    int bi  = swz >> 7;              // b*64 + i  (0..127)
    int mid = swz & 127;
    int ct  = mid >> 1;              // channel tile (64 ch), 0..63
    int jh  = mid & 1;               // j half (32 j's)
    int b = bi >> 6, i = bi & 63;
    int c0 = ct * 64;
    int t  = threadIdx.x;
    int pbase = bi * 64 + jh * 32;

    // ---- phase 1: async stage raw corner slices ----
    int w    = t >> 6;               // wave id 0..3
    int lane = t & 63;
    int m    = lane & 15;            // 16-B chunk within 256-B corner slice
    int c2   = lane >> 4;            // corner 0..3
    #pragma unroll
    for (int r = 0; r < 8; ++r) {
        int j2 = w * 8 + r;          // wave-uniform
        int4 o = offs[pbase + j2];
        int offsel = c2 < 2 ? (c2 == 0 ? o.x : o.y)
                            : (c2 == 2 ? o.z : o.w);
        const float* gp = gauss + (size_t)(offsel + c0)
                        + ((m ^ (j2 & 15)) << 2);
        load_lds16(gp, &ldsbuf[j2 * 256]);
    }
    __syncthreads();   // drains vmcnt(0): all 8 per-wave async loads

    // ---- phase 2: combine + coalesced NT stores ----
    int j2 = t & 31;
    int cg = t >> 5;                 // 0..7, handles ch-quads 2cg, 2cg+1
    float4 wt = wts[pbase + j2];
    size_t obase = (size_t)b * 16777216 + (size_t)c0 * 4096
                 + (size_t)i * 64 + jh * 32 + j2;
    int sbase = j2 * 256;
    int f = j2 & 15;
    #pragma unroll
    for (int u = 0; u < 2; ++u) {
        int q = cg * 2 + u;          // channel quad 0..15
        int pos = (q ^ f) * 4;
        f32x4 A = *(const f32x4*)&ldsbuf[sbase +       pos];
        f32x4 B = *(const f32x4*)&ldsbuf[sbase +  64 + pos];
        f32x4 C = *(const f32x4*)&ldsbuf[sbase + 128 + pos];
        f32x4 D = *(const f32x4*)&ldsbuf[sbase + 192 + pos];
        f32x4 res = wt.x * A + wt.y * B + wt.z * C + wt.w * D;
        float* po = out + obase + (size_t)(q * 4) * 4096;
        __builtin_nontemporal_store(res.x, po);
        __builtin_nontemporal_store(res.y, po + 4096);
        __builtin_nontemporal_store(res.z, po + 8192);
        __builtin_nontemporal_store(res.w, po + 12288);
    }
}

extern "C" void kernel_launch(void* const* d_in, const int* in_sizes, int n_in,
                              void* d_out, int out_size, void* d_ws, size_t ws_size,
                              hipStream_t stream) {
    const float* feat  = (const float*)d_in[0];
    const float* gauss = (const float*)d_in[1];
    const float* W_in  = (const float*)d_in[2];
    const float* b_in  = (const float*)d_in[3];
    const float* W_dw  = (const float*)d_in[4];
    const float* b_dw  = (const float*)d_in[5];
    const float* W_ofs = (const float*)d_in[6];
    const float* W_a   = (const float*)d_in[7];
    const float* b_a   = (const float*)d_in[8];
    const float* lam   = (const float*)d_in[9];
    float* out = (float*)d_out;

    float* fm   = (float*)d_ws;
    int4*  offs = (int4*)((char*)d_ws + 32768);
    float4* wts = (float4*)((char*)d_ws + 32768 + 131072);

    k_mean  <<<NB * HW, 256, 0, stream>>>(feat, fm);
    k_params<<<32, 256, 0, stream>>>(fm, W_in, b_in, W_dw, b_dw,
                                     W_ofs, W_a, b_a, lam, offs, wts);
    k_sample<<<NB * HW * 128, 256, 0, stream>>>(gauss, offs, wts, out);
}

// Round 8
// 63.519 us; speedup vs baseline: 1.7740x; 1.7740x over previous
//
#include <hip/hip_runtime.h>
#include <math.h>

// Problem constants
#define HW 64
#define NB 2
#define NCIN 128
#define NCH 32

typedef float f32x4 __attribute__((ext_vector_type(4)));

// ws layout:
//   fm   : float[2*64*64]            @ 0        (32768 B)
//   offs : int4 [8192]               @ 32768    (131072 B)
//   wts  : float4[8192]              @ 163840   (131072 B)

// ---------------- kernel 1: fm = mean over 128 channels ----------------
__global__ __launch_bounds__(256) void k_mean(const float* __restrict__ feat,
                                              float* __restrict__ fm) {
    int bh = blockIdx.x;            // b*64 + h
    int w  = threadIdx.x & 63;
    int cg = threadIdx.x >> 6;      // 0..3, each sums 32 channels
    int b = bh >> 6, h = bh & 63;
    const float* base = feat + ((size_t)(b * NCIN) * 64 + h) * 64 + w;
    float s = 0.f;
    #pragma unroll
    for (int c = 0; c < 32; ++c)
        s += base[(size_t)(cg * 32 + c) * 4096];
    __shared__ float red[4][64];
    red[cg][w] = s;
    __syncthreads();
    if (cg == 0) {
        float tot = red[0][w] + red[1][w] + red[2][w] + red[3][w];
        fm[bh * 64 + w] = tot * (1.f / 128.f);
    }
}

// ------------- kernel 2: per-position offsets/weights/gain -------------
__global__ __launch_bounds__(256) void k_params(
    const float* __restrict__ fm,
    const float* __restrict__ W_in, const float* __restrict__ b_in,
    const float* __restrict__ W_dw, const float* __restrict__ b_dw,
    const float* __restrict__ W_ofs, const float* __restrict__ W_a,
    const float* __restrict__ b_a, const float* __restrict__ lam,
    int4* __restrict__ offs, float4* __restrict__ wts)
{
    __shared__ float WD[NCH * 25];
    __shared__ float Wi[NCH], Bi[NCH], Bd[NCH], Wo0[NCH], Wo1[NCH], Wa_s[NCH];
    int t = threadIdx.x;
    for (int k = t; k < NCH * 25; k += 256) WD[k] = W_dw[k];
    if (t < NCH) {
        Wi[t]  = W_in[t];  Bi[t]  = b_in[t]; Bd[t] = b_dw[t];
        Wo0[t] = W_ofs[t]; Wo1[t] = W_ofs[NCH + t];
        Wa_s[t] = W_a[t];
    }
    __syncthreads();

    int p = blockIdx.x * 256 + t;   // 0..8191
    int b = p >> 12;
    int i = (p >> 6) & 63;
    int j = p & 63;

    // 5x5 replicate-padded patch of fm
    float patch[25];
    #pragma unroll
    for (int dy = 0; dy < 5; ++dy) {
        int ry = i + dy - 2; ry = ry < 0 ? 0 : (ry > 63 ? 63 : ry);
        #pragma unroll
        for (int dx = 0; dx < 5; ++dx) {
            int rx = j + dx - 2; rx = rx < 0 ? 0 : (rx > 63 ? 63 : rx);
            patch[dy * 5 + dx] = fm[(b * 64 + ry) * 64 + rx];
        }
    }
    float fmc = patch[12];

    float a0 = 0.f, a1 = 0.f, kA = 0.f, kB = 0.f;
    for (int c = 0; c < NCH; ++c) {
        float s = 0.f, sw = 0.f;
        #pragma unroll
        for (int q = 0; q < 25; ++q) {
            float wv = WD[c * 25 + q];
            s  += patch[q] * wv;
            sw += wv;
        }
        float pre = Wi[c] * s + Bi[c] * sw + Bd[c];
        float zc = pre > 0.f ? pre : 0.f;
        a0 += zc * Wo0[c];
        a1 += zc * Wo1[c];
        kA += Wi[c] * Wa_s[c];
        kB += Bi[c] * Wa_s[c];
    }
    float ga = 1.f + lam[0] * (fmc * kA + kB + b_a[0]);

    float yy = (i + 0.5f) * (1.f / 32.f) - 1.f;
    float xx = (j + 0.5f) * (1.f / 32.f) - 1.f;
    float pos0 = fminf(fmaxf((100.f / 64.f) * tanhf(a0) + yy, -1.f), 1.f); // y
    float pos1 = fminf(fmaxf((100.f / 64.f) * tanhf(a1) + xx, -1.f), 1.f); // x
    float y = (pos0 + 1.f) * 0.5f * 63.f;
    float x = (pos1 + 1.f) * 0.5f * 63.f;
    float y0 = floorf(y), x0 = floorf(x);
    float wy1 = y - y0, wx1 = x - x0;
    float wy0 = 1.f - wy1, wx0 = 1.f - wx1;
    int y0i = (int)y0; y0i = y0i < 0 ? 0 : (y0i > 63 ? 63 : y0i);
    int x0i = (int)x0; x0i = x0i < 0 ? 0 : (x0i > 63 ? 63 : x0i);
    int y1i = y0i + 1 > 63 ? 63 : y0i + 1;
    int x1i = x0i + 1 > 63 ? 63 : x0i + 1;

    int basep = b * 16777216;
    offs[p] = make_int4(basep + (y0i * 64 + x0i) * 4096,
                        basep + (y0i * 64 + x1i) * 4096,
                        basep + (y1i * 64 + x0i) * 4096,
                        basep + (y1i * 64 + x1i) * 4096);
    wts[p] = make_float4(wy0 * wx0 * ga, wy0 * wx1 * ga,
                         wy1 * wx0 * ga, wy1 * wx1 * ga);
}

// ------------- kernel 3: gather-sample + LDS transpose + write -------------
// block = (b, i, channel-tile of 64); 256 threads
// phase1: thread (q=t&15, jg=t>>4) loads f32x4 per corner; ALL 16 gather
//         results are tied by ONE volatile asm ("+v" operands) so the
//         compiler cannot sink any load past that point -> 16-deep MLP.
// phase2: thread (jq=t&15, cg=t>>4) writes f32x4 along j, nontemporal
__global__ __launch_bounds__(256) void k_sample(
    const float* __restrict__ gauss,
    const int4* __restrict__ offs, const float4* __restrict__ wts,
    float* __restrict__ out)
{
    __shared__ float lds[64 * 65];
    int bid = blockIdx.x;
    // bijective XCD swizzle: 8192 % 8 == 0
    int swz = (bid & 7) * 1024 + (bid >> 3);
    int ct = swz & 63;              // channel tile (64 channels)
    int bi = swz >> 6;              // b*64 + i
    int b = bi >> 6, i = bi & 63;
    int c0 = ct * 64;
    int t  = threadIdx.x;
    int pbase = bi * 64;

    int q  = t & 15;                // channel quad: channels 4q..4q+3
    int jg = t >> 4;                // 0..15

    // ---- hoist all offset/weight loads ----
    int4   off[4];
    float4 wt[4];
    #pragma unroll
    for (int it = 0; it < 4; ++it) {
        off[it] = offs[pbase + it * 16 + jg];
        wt[it]  = wts[pbase + it * 16 + jg];
    }

    // ---- issue all 16 gather loads ----
    f32x4 A0 = *((const f32x4*)(gauss + off[0].x + c0) + q);
    f32x4 B0 = *((const f32x4*)(gauss + off[0].y + c0) + q);
    f32x4 C0 = *((const f32x4*)(gauss + off[0].z + c0) + q);
    f32x4 D0 = *((const f32x4*)(gauss + off[0].w + c0) + q);
    f32x4 A1 = *((const f32x4*)(gauss + off[1].x + c0) + q);
    f32x4 B1 = *((const f32x4*)(gauss + off[1].y + c0) + q);
    f32x4 C1 = *((const f32x4*)(gauss + off[1].z + c0) + q);
    f32x4 D1 = *((const f32x4*)(gauss + off[1].w + c0) + q);
    f32x4 A2 = *((const f32x4*)(gauss + off[2].x + c0) + q);
    f32x4 B2 = *((const f32x4*)(gauss + off[2].y + c0) + q);
    f32x4 C2 = *((const f32x4*)(gauss + off[2].z + c0) + q);
    f32x4 D2 = *((const f32x4*)(gauss + off[2].w + c0) + q);
    f32x4 A3 = *((const f32x4*)(gauss + off[3].x + c0) + q);
    f32x4 B3 = *((const f32x4*)(gauss + off[3].y + c0) + q);
    f32x4 C3 = *((const f32x4*)(gauss + off[3].z + c0) + q);
    f32x4 D3 = *((const f32x4*)(gauss + off[3].w + c0) + q);

    // ONE fence consuming all 16 results: every load must be issued (and
    // waited) before this point -> 16 loads in flight per thread.
    asm volatile("" : "+v"(A0), "+v"(B0), "+v"(C0), "+v"(D0),
                      "+v"(A1), "+v"(B1), "+v"(C1), "+v"(D1),
                      "+v"(A2), "+v"(B2), "+v"(C2), "+v"(D2),
                      "+v"(A3), "+v"(B3), "+v"(C3), "+v"(D3));

    // ---- combine + LDS transpose write ----
    int cb = 4 * q;
    {
        f32x4 r;
        int j;
        j = jg;
        r = wt[0].x * A0 + wt[0].y * B0 + wt[0].z * C0 + wt[0].w * D0;
        lds[(cb + 0) * 65 + j] = r.x; lds[(cb + 1) * 65 + j] = r.y;
        lds[(cb + 2) * 65 + j] = r.z; lds[(cb + 3) * 65 + j] = r.w;
        j = 16 + jg;
        r = wt[1].x * A1 + wt[1].y * B1 + wt[1].z * C1 + wt[1].w * D1;
        lds[(cb + 0) * 65 + j] = r.x; lds[(cb + 1) * 65 + j] = r.y;
        lds[(cb + 2) * 65 + j] = r.z; lds[(cb + 3) * 65 + j] = r.w;
        j = 32 + jg;
        r = wt[2].x * A2 + wt[2].y * B2 + wt[2].z * C2 + wt[2].w * D2;
        lds[(cb + 0) * 65 + j] = r.x; lds[(cb + 1) * 65 + j] = r.y;
        lds[(cb + 2) * 65 + j] = r.z; lds[(cb + 3) * 65 + j] = r.w;
        j = 48 + jg;
        r = wt[3].x * A3 + wt[3].y * B3 + wt[3].z * C3 + wt[3].w * D3;
        lds[(cb + 0) * 65 + j] = r.x; lds[(cb + 1) * 65 + j] = r.y;
        lds[(cb + 2) * 65 + j] = r.z; lds[(cb + 3) * 65 + j] = r.w;
    }
    __syncthreads();

    // phase 2: out[b, c0+c, i, 4*jq .. 4*jq+3], nontemporal f32x4
    size_t obase = (size_t)b * 16777216 + (size_t)c0 * 4096 + (size_t)i * 64;
    int jq = t & 15;                // j quad
    int cg = t >> 4;                // 0..15
    #pragma unroll
    for (int it = 0; it < 4; ++it) {
        int c = it * 16 + cg;
        f32x4 v;
        v.x = lds[c * 65 + 4 * jq + 0];
        v.y = lds[c * 65 + 4 * jq + 1];
        v.z = lds[c * 65 + 4 * jq + 2];
        v.w = lds[c * 65 + 4 * jq + 3];
        __builtin_nontemporal_store(v, (f32x4*)(out + obase + (size_t)c * 4096 + 4 * jq));
    }
}

extern "C" void kernel_launch(void* const* d_in, const int* in_sizes, int n_in,
                              void* d_out, int out_size, void* d_ws, size_t ws_size,
                              hipStream_t stream) {
    const float* feat  = (const float*)d_in[0];
    const float* gauss = (const float*)d_in[1];
    const float* W_in  = (const float*)d_in[2];
    const float* b_in  = (const float*)d_in[3];
    const float* W_dw  = (const float*)d_in[4];
    const float* b_dw  = (const float*)d_in[5];
    const float* W_ofs = (const float*)d_in[6];
    const float* W_a   = (const float*)d_in[7];
    const float* b_a   = (const float*)d_in[8];
    const float* lam   = (const float*)d_in[9];
    float* out = (float*)d_out;

    float* fm   = (float*)d_ws;
    int4*  offs = (int4*)((char*)d_ws + 32768);
    float4* wts = (float4*)((char*)d_ws + 32768 + 131072);

    k_mean  <<<NB * HW, 256, 0, stream>>>(feat, fm);
    k_params<<<32, 256, 0, stream>>>(fm, W_in, b_in, W_dw, b_dw,
                                     W_ofs, W_a, b_a, lam, offs, wts);
    k_sample<<<NB * HW * 64, 256, 0, stream>>>(gauss, offs, wts, out);
}

// Round 9
// 63.114 us; speedup vs baseline: 1.7854x; 1.0064x over previous
//
#include <hip/hip_runtime.h>
#include <math.h>

// Problem constants
#define HW 64
#define NB 2
#define NCIN 128
#define NCH 32

typedef float f32x4 __attribute__((ext_vector_type(4)));

// ws layout:
//   fm   : float[2*64*64]            @ 0        (32768 B)
//   offs : int4 [8192]               @ 32768    (131072 B)
//   wts  : float4[8192]              @ 163840   (131072 B)

// ---------------- kernel 1: fm = mean over 128 channels ----------------
__global__ __launch_bounds__(256) void k_mean(const float* __restrict__ feat,
                                              float* __restrict__ fm) {
    int bh = blockIdx.x;            // b*64 + h
    int w  = threadIdx.x & 63;
    int cg = threadIdx.x >> 6;      // 0..3, each sums 32 channels
    int b = bh >> 6, h = bh & 63;
    const float* base = feat + ((size_t)(b * NCIN) * 64 + h) * 64 + w;
    float s = 0.f;
    #pragma unroll
    for (int c = 0; c < 32; ++c)
        s += base[(size_t)(cg * 32 + c) * 4096];
    __shared__ float red[4][64];
    red[cg][w] = s;
    __syncthreads();
    if (cg == 0) {
        float tot = red[0][w] + red[1][w] + red[2][w] + red[3][w];
        fm[bh * 64 + w] = tot * (1.f / 128.f);
    }
}

// ------------- kernel 2: per-position offsets/weights/gain -------------
__global__ __launch_bounds__(256) void k_params(
    const float* __restrict__ fm,
    const float* __restrict__ W_in, const float* __restrict__ b_in,
    const float* __restrict__ W_dw, const float* __restrict__ b_dw,
    const float* __restrict__ W_ofs, const float* __restrict__ W_a,
    const float* __restrict__ b_a, const float* __restrict__ lam,
    int4* __restrict__ offs, float4* __restrict__ wts)
{
    __shared__ float WD[NCH * 25];
    __shared__ float Wi[NCH], Bi[NCH], Bd[NCH], Wo0[NCH], Wo1[NCH], Wa_s[NCH];
    int t = threadIdx.x;
    for (int k = t; k < NCH * 25; k += 256) WD[k] = W_dw[k];
    if (t < NCH) {
        Wi[t]  = W_in[t];  Bi[t]  = b_in[t]; Bd[t] = b_dw[t];
        Wo0[t] = W_ofs[t]; Wo1[t] = W_ofs[NCH + t];
        Wa_s[t] = W_a[t];
    }
    __syncthreads();

    int p = blockIdx.x * 256 + t;   // 0..8191
    int b = p >> 12;
    int i = (p >> 6) & 63;
    int j = p & 63;

    // 5x5 replicate-padded patch of fm
    float patch[25];
    #pragma unroll
    for (int dy = 0; dy < 5; ++dy) {
        int ry = i + dy - 2; ry = ry < 0 ? 0 : (ry > 63 ? 63 : ry);
        #pragma unroll
        for (int dx = 0; dx < 5; ++dx) {
            int rx = j + dx - 2; rx = rx < 0 ? 0 : (rx > 63 ? 63 : rx);
            patch[dy * 5 + dx] = fm[(b * 64 + ry) * 64 + rx];
        }
    }
    float fmc = patch[12];

    float a0 = 0.f, a1 = 0.f, kA = 0.f, kB = 0.f;
    for (int c = 0; c < NCH; ++c) {
        float s = 0.f, sw = 0.f;
        #pragma unroll
        for (int q = 0; q < 25; ++q) {
            float wv = WD[c * 25 + q];
            s  += patch[q] * wv;
            sw += wv;
        }
        float pre = Wi[c] * s + Bi[c] * sw + Bd[c];
        float zc = pre > 0.f ? pre : 0.f;
        a0 += zc * Wo0[c];
        a1 += zc * Wo1[c];
        kA += Wi[c] * Wa_s[c];
        kB += Bi[c] * Wa_s[c];
    }
    float ga = 1.f + lam[0] * (fmc * kA + kB + b_a[0]);

    float yy = (i + 0.5f) * (1.f / 32.f) - 1.f;
    float xx = (j + 0.5f) * (1.f / 32.f) - 1.f;
    float pos0 = fminf(fmaxf((100.f / 64.f) * tanhf(a0) + yy, -1.f), 1.f); // y
    float pos1 = fminf(fmaxf((100.f / 64.f) * tanhf(a1) + xx, -1.f), 1.f); // x
    float y = (pos0 + 1.f) * 0.5f * 63.f;
    float x = (pos1 + 1.f) * 0.5f * 63.f;
    float y0 = floorf(y), x0 = floorf(x);
    float wy1 = y - y0, wx1 = x - x0;
    float wy0 = 1.f - wy1, wx0 = 1.f - wx1;
    int y0i = (int)y0; y0i = y0i < 0 ? 0 : (y0i > 63 ? 63 : y0i);
    int x0i = (int)x0; x0i = x0i < 0 ? 0 : (x0i > 63 ? 63 : x0i);
    int y1i = y0i + 1 > 63 ? 63 : y0i + 1;
    int x1i = x0i + 1 > 63 ? 63 : x0i + 1;

    int basep = b * 16777216;
    offs[p] = make_int4(basep + (y0i * 64 + x0i) * 4096,
                        basep + (y0i * 64 + x1i) * 4096,
                        basep + (y1i * 64 + x0i) * 4096,
                        basep + (y1i * 64 + x1i) * 4096);
    wts[p] = make_float4(wy0 * wx0 * ga, wy0 * wx1 * ga,
                         wy1 * wx0 * ga, wy1 * wx1 * ga);
}

// ------------- kernel 3: gather-sample, 128-ch x 32-j tile -------------
// block = (bi, ct of 128 channels, jh of 32 j's); 256 threads; LDS 16 KB.
// phase1: thread (h=t&31 -> ch quad 4h, js=t>>5): per corner load is 512 B
//         contiguous over 32 lanes => 2 segments per wave-instr; 4 iters.
// phase2: thread (j2=t&31, cg=t>>5): b128 swizzled LDS read + scalar NT
//         stores, 128-B contiguous per half-wave.
// LDS swizzle: word(j, C) = j*128 + 4*(C ^ (j&15))  (C = ch-quad 0..31)
__global__ __launch_bounds__(256) void k_sample(
    const float* __restrict__ gauss,
    const int4* __restrict__ offs, const float4* __restrict__ wts,
    float* __restrict__ out)
{
    __shared__ float lds[32 * 128];  // 16 KB
    int bid = blockIdx.x;
    // bijective XCD swizzle: 8192 % 8 == 0; same-bi tiles land on one XCD
    int swz = (bid & 7) * 1024 + (bid >> 3);
    int bi  = swz >> 6;              // b*64 + i
    int ct  = (swz >> 1) & 31;       // channel tile (128 ch)
    int jh  = swz & 1;               // j half (32 j's)
    int b = bi >> 6, i = bi & 63;
    int c0 = ct * 128;
    int t  = threadIdx.x;
    int pbase = bi * 64 + jh * 32;

    int h  = t & 31;                // channel quad: channels 4h..4h+3
    int js = t >> 5;                // 0..7

    #pragma unroll
    for (int r = 0; r < 4; ++r) {
        int j = r * 8 + js;
        int4  off = offs[pbase + j];
        float4 wt = wts[pbase + j];
        f32x4 A = *((const f32x4*)(gauss + off.x + c0) + h);
        f32x4 B = *((const f32x4*)(gauss + off.y + c0) + h);
        f32x4 C = *((const f32x4*)(gauss + off.z + c0) + h);
        f32x4 D = *((const f32x4*)(gauss + off.w + c0) + h);
        f32x4 res = wt.x * A + wt.y * B + wt.z * C + wt.w * D;
        *(f32x4*)&lds[j * 128 + 4 * (h ^ (j & 15))] = res;
    }
    __syncthreads();

    // phase 2: out[b, c0+4*q+u, i, jh*32 + j2]
    size_t obase = (size_t)b * 16777216 + (size_t)c0 * 4096
                 + (size_t)i * 64 + jh * 32;
    int j2 = t & 31;
    int cg = t >> 5;                 // 0..7; handles ch-quads m*8+cg
    int f  = j2 & 15;
    #pragma unroll
    for (int m = 0; m < 4; ++m) {
        int q = m * 8 + cg;          // channel quad 0..31
        f32x4 v = *(const f32x4*)&lds[j2 * 128 + 4 * (q ^ f)];
        float* po = out + obase + (size_t)(q * 4) * 4096 + j2;
        __builtin_nontemporal_store(v.x, po);
        __builtin_nontemporal_store(v.y, po + 4096);
        __builtin_nontemporal_store(v.z, po + 8192);
        __builtin_nontemporal_store(v.w, po + 12288);
    }
}

extern "C" void kernel_launch(void* const* d_in, const int* in_sizes, int n_in,
                              void* d_out, int out_size, void* d_ws, size_t ws_size,
                              hipStream_t stream) {
    const float* feat  = (const float*)d_in[0];
    const float* gauss = (const float*)d_in[1];
    const float* W_in  = (const float*)d_in[2];
    const float* b_in  = (const float*)d_in[3];
    const float* W_dw  = (const float*)d_in[4];
    const float* b_dw  = (const float*)d_in[5];
    const float* W_ofs = (const float*)d_in[6];
    const float* W_a   = (const float*)d_in[7];
    const float* b_a   = (const float*)d_in[8];
    const float* lam   = (const float*)d_in[9];
    float* out = (float*)d_out;

    float* fm   = (float*)d_ws;
    int4*  offs = (int4*)((char*)d_ws + 32768);
    float4* wts = (float4*)((char*)d_ws + 32768 + 131072);

    k_mean  <<<NB * HW, 256, 0, stream>>>(feat, fm);
    k_params<<<32, 256, 0, stream>>>(fm, W_in, b_in, W_dw, b_dw,
                                     W_ofs, W_a, b_a, lam, offs, wts);
    k_sample<<<NB * HW * 64, 256, 0, stream>>>(gauss, offs, wts, out);
}